// Round 8
// baseline (63.565 us; speedup 1.0000x reference)
//
#include <hip/hip_runtime.h>

typedef __attribute__((ext_vector_type(4))) float f32x4;
typedef __attribute__((ext_vector_type(8))) short bf16x8;

constexpr float EFF_DT = 0.01f;   // DT * DT_SCALE
constexpr float HH     = 0.005f;  // 0.5 * eff_dt ; mu = 0

__device__ inline short f2bf(float x){
    union{float f;unsigned u;}c; c.f=x;
    unsigned r=c.u+0x7FFFu+((c.u>>16)&1u);   // RNE
    return (short)(r>>16);
}
__device__ inline unsigned cvtpk(float lo,float hi){
    unsigned r; asm("v_cvt_pk_bf16_f32 %0, %1, %2":"=v"(r):"v"(lo),"v"(hi)); return r;
}
__device__ inline float ubflo(unsigned u){union{unsigned x;float f;}c;c.x=u<<16;return c.f;}
__device__ inline float ubfhi(unsigned u){union{unsigned x;float f;}c;c.x=u&0xffff0000u;return c.f;}

union VP4 { unsigned u[4]; bf16x8 h; };

// Block = 128 threads = 2 waves; block owns 16 batch rows; wave dh owns d-half
// d in [dh*128, dh*128+128). Lane (g=lane>>4, c=lane&15) holds, for local tiles
// i=0..7 (global dt=dh*8+i), elements d = dt*16+g*4+j of batch row (R0+c).
// Phase A computes PARTIAL T (K=128); the wave pair exchanges partials through
// LDS (fp32, summed BEFORE squaring -> same numerics as r7), 1 barrier/half-step,
// double-buffered by `half` parity. WF tiles are wave-private (no init barrier).
// State all in regs: vv (32) + xacc fp32 fma-accum (32) + fpk (16); uf 32 (RO).
// launch_bounds(128,3): 3 waves/SIMD (unified budget 170 >= ~140 demand).
__global__ __launch_bounds__(128,3) void leapfrog_v9(
    const float* __restrict__ x_in, const float* __restrict__ v_in,
    const float* __restrict__ f_in, const float* __restrict__ Ug,
    const float* __restrict__ Wg, const int* __restrict__ steps_p,
    float* __restrict__ out)
{
    __shared__ __align__(16) char lds[32768];
    short* WF  = (short*)lds;              // 16KB: [16 dt][64 lane][8 shorts], wave-private halves
    f32x4* TEX = (f32x4*)(lds + 16384);    // 16KB: [2 buf][2 dh][2 rt][64 lane] f32x4, lane-linear

    const int tid=threadIdx.x, dh=tid>>6, lane=tid&63, g=lane>>4, c=lane&15;
    const int R0 = blockIdx.x*16;
    const int gb = (R0+c)*256 + g*4;
    const int BD = 32768*256;
    const int db = dh*8;                   // global dt base for this wave

    f32x4 vv[8], xacc[8];
    unsigned fpk[8][2];
    bf16x8 uf[2][4];

    // ---- v first (gates first MFMA), then x (needed only at first ACCX) ----
    #pragma unroll
    for(int i=0;i<8;++i) vv[i] = *(const f32x4*)&v_in[gb + (db+i)*16];
    #pragma unroll
    for(int i=0;i<8;++i) xacc[i] = *(const f32x4*)&x_in[gb + (db+i)*16];

    // ---- uf: U^T A-frags for own K-half (global cc = dh*4+cq), L2-hot gathers ----
    #pragma unroll
    for(int rt=0;rt<2;++rt){
        #pragma unroll
        for(int cq=0;cq<4;++cq){
            bf16x8 e;
            #pragma unroll
            for(int j=0;j<8;++j){
                const int kk = ((j>>2)<<4) + g*4 + (j&3);        // kmap(g,j)
                e[j] = f2bf(Ug[((dh*4+cq)*32+kk)*32 + rt*16 + c]); // U[d][r]
            }
            uf[rt][cq] = e;
        }
    }
    // ---- WF: (HH*W)^T A-frags for own 8 dt tiles (wave-private, no barrier) ----
    #pragma unroll
    for(int i=0;i<8;++i){
        const int t = db + i;
        bf16x8 e;
        #pragma unroll
        for(int j=0;j<8;++j){
            const int kk = ((j>>2)<<4) + g*4 + (j&3);
            e[j] = f2bf(HH * Wg[kk*256 + t*16 + c]);             // HH*W[r][d]
        }
        *(bf16x8*)&WF[t*512 + lane*8] = e;
    }
    // ---- f -> packed bf16(h*f) regs ----
    #pragma unroll
    for(int i=0;i<8;++i){
        f32x4 ff = *(const f32x4*)&f_in[gb + (db+i)*16];
        fpk[i][0]=cvtpk(HH*ff[0],HH*ff[1]);
        fpk[i][1]=cvtpk(HH*ff[2],HH*ff[3]);
    }

    const int nsteps = *steps_p;
    const f32x4 zero = {0.f,0.f,0.f,0.f};

    // HALF selects the exchange buffer (compile-time: buf parity == half parity;
    // one barrier per half-step separates partner-read from the next overwrite).
#define PH(HALF, ACCX, STX, STV) do{ \
    f32x4 a00=zero,a01=zero,a10=zero,a11=zero; \
    _Pragma("unroll") \
    for(int cq=0;cq<4;++cq){ \
        VP4 vp; \
        vp.u[0]=cvtpk(vv[2*cq][0],  vv[2*cq][1]); \
        vp.u[1]=cvtpk(vv[2*cq][2],  vv[2*cq][3]); \
        vp.u[2]=cvtpk(vv[2*cq+1][0],vv[2*cq+1][1]); \
        vp.u[3]=cvtpk(vv[2*cq+1][2],vv[2*cq+1][3]); \
        if(cq&1){ a01=__builtin_amdgcn_mfma_f32_16x16x32_bf16(uf[0][cq],vp.h,a01,0,0,0); \
                  a11=__builtin_amdgcn_mfma_f32_16x16x32_bf16(uf[1][cq],vp.h,a11,0,0,0); } \
        else    { a00=__builtin_amdgcn_mfma_f32_16x16x32_bf16(uf[0][cq],vp.h,a00,0,0,0); \
                  a10=__builtin_amdgcn_mfma_f32_16x16x32_bf16(uf[1][cq],vp.h,a10,0,0,0); } \
    } \
    f32x4 p0, p1; \
    p0[0]=a00[0]+a01[0]; p0[1]=a00[1]+a01[1]; p0[2]=a00[2]+a01[2]; p0[3]=a00[3]+a01[3]; \
    p1[0]=a10[0]+a11[0]; p1[1]=a10[1]+a11[1]; p1[2]=a10[2]+a11[2]; p1[3]=a10[3]+a11[3]; \
    TEX[(((HALF)*2+dh)*2+0)*64+lane]=p0; \
    TEX[(((HALF)*2+dh)*2+1)*64+lane]=p1; \
    __syncthreads(); \
    { \
        f32x4 q0=TEX[(((HALF)*2+(1-dh))*2+0)*64+lane]; \
        f32x4 q1=TEX[(((HALF)*2+(1-dh))*2+1)*64+lane]; \
        float s0=p0[0]+q0[0], s1=p0[1]+q0[1], s2=p0[2]+q0[2], s3=p0[3]+q0[3]; \
        float s4=p1[0]+q1[0], s5=p1[1]+q1[1], s6=p1[2]+q1[2], s7=p1[3]+q1[3]; \
        VP4 t2; \
        t2.u[0]=cvtpk(s0*s0, s1*s1); \
        t2.u[1]=cvtpk(s2*s2, s3*s3); \
        t2.u[2]=cvtpk(s4*s4, s5*s5); \
        t2.u[3]=cvtpk(s6*s6, s7*s7); \
        _Pragma("unroll") \
        for(int i=0;i<8;++i){ \
            bf16x8 wf=*(bf16x8*)&WF[(db+i)*512 + lane*8]; \
            f32x4 gm=__builtin_amdgcn_mfma_f32_16x16x32_bf16(wf,t2.h,zero,0,0,0); \
            const unsigned f0=fpk[i][0], f1=fpk[i][1]; \
            f32x4 nv; \
            nv[0]=(vv[i][0]+ubflo(f0))-gm[0]; \
            nv[1]=(vv[i][1]+ubfhi(f0))-gm[1]; \
            nv[2]=(vv[i][2]+ubflo(f1))-gm[2]; \
            nv[3]=(vv[i][3]+ubfhi(f1))-gm[3]; \
            vv[i]=nv; \
            if(ACCX){ \
                xacc[i][0]=fmaf(EFF_DT,nv[0],xacc[i][0]); \
                xacc[i][1]=fmaf(EFF_DT,nv[1],xacc[i][1]); \
                xacc[i][2]=fmaf(EFF_DT,nv[2],xacc[i][2]); \
                xacc[i][3]=fmaf(EFF_DT,nv[3],xacc[i][3]); \
                if(STX){ *(f32x4*)&out[gb+(db+i)*16] = xacc[i]; } \
            } \
            if(STV){ *(f32x4*)&out[BD+gb+(db+i)*16] = nv; } \
        } \
    } \
}while(0)

    for(int s=0;s<nsteps-1;++s){
        PH(0, 1,0,0);      // half 0: v_half ; x += dt*v_half (fma, ref-exact recurrence)
        PH(1, 0,0,0);      // half 1: v update
    }
    PH(0, 1,1,0);          // last half 0: x final -> store x (write drains early)
    PH(1, 0,0,1);          // last half 1: v final -> store v
#undef PH
}

extern "C" void kernel_launch(void* const* d_in, const int* in_sizes, int n_in,
                              void* d_out, int out_size, void* d_ws, size_t ws_size,
                              hipStream_t stream) {
    (void)in_sizes; (void)n_in; (void)d_ws; (void)ws_size; (void)out_size;
    const float* x_in = (const float*)d_in[0];
    const float* v_in = (const float*)d_in[1];
    const float* f_in = (const float*)d_in[2];
    const float* Ug   = (const float*)d_in[3];
    const float* Wg   = (const float*)d_in[4];
    const int*   st   = (const int*)d_in[5];
    float* out = (float*)d_out;

    dim3 grid(32768/16), block(128);
    hipLaunchKernelGGL(leapfrog_v9, grid, block, 0, stream,
                       x_in, v_in, f_in, Ug, Wg, st, out);
}

// Round 9
// 44.163 us; speedup vs baseline: 1.4393x; 1.4393x over previous
//
#include <hip/hip_runtime.h>

typedef __attribute__((ext_vector_type(4))) float f32x4;
typedef __attribute__((ext_vector_type(8))) short bf16x8;

constexpr float EFF_DT = 0.01f;   // DT * DT_SCALE
constexpr float HH     = 0.005f;  // 0.5 * eff_dt ; mu = 0
constexpr float INV_DT = 100.0f;  // 1 / EFF_DT

__device__ inline short f2bf(float x){
    union{float f;unsigned u;}c; c.f=x;
    unsigned r=c.u+0x7FFFu+((c.u>>16)&1u);   // RNE
    return (short)(r>>16);
}
__device__ inline unsigned cvtpk(float lo,float hi){
    unsigned r; asm("v_cvt_pk_bf16_f32 %0, %1, %2":"=v"(r):"v"(lo),"v"(hi)); return r;
}
__device__ inline float ubflo(unsigned u){union{unsigned x;float f;}c;c.x=u<<16;return c.f;}
__device__ inline float ubfhi(unsigned u){union{unsigned x;float f;}c;c.x=u&0xffff0000u;return c.f;}

union VP4 { unsigned u[4]; bf16x8 h; };

// r7 structure (proven 48.6us) + MFMA-C fusion of the v-update.
// Block = 256 threads (4 waves); each wave owns 16 batch rows; main loop barrier-free.
// Lane (g=lane>>4, c=lane&15) holds d = dt*16 + g*4 + j of batch row (R0+c) for all dt.
// Register regime (r5/r6/r8 lessons): (256,2) -> 128 arch + 128 acc; VALU-active =
// vv(64)+fpk(32)+temps fits 128; uf[2][8] read-only -> AGPR; xacc fp32 in per-wave LDS.
// FUSION: WF holds -HH*W, phase B computes nv = mfma(wf, t2, cin) with cin = vv + h*f,
// so the -h*Gamma subtraction rides in the MFMA fp32 accumulator (removes 64 VALU/
// half-step and shortens the gm->vv dependency).
__global__ __launch_bounds__(256,2) void leapfrog_v10(
    const float* __restrict__ x_in, const float* __restrict__ v_in,
    const float* __restrict__ f_in, const float* __restrict__ Ug,
    const float* __restrict__ Wg, const int* __restrict__ steps_p,
    float* __restrict__ out)
{
    __shared__ __align__(16) char lds[81920];
    short* WF = (short*)lds;                       // 16KB: (-HH*W)^T A-frags

    const int tid=threadIdx.x, w=tid>>6, lane=tid&63, g=lane>>4, c=lane&15;
    const int R0 = blockIdx.x*64 + w*16;
    const int gb = (R0+c)*256 + g*4;
    const int BD = 32768*256;
    float* xw = (float*)(lds + 16384 + w*16384);   // per-wave xacc [16 dt][64 lane][4]

    // ---- persistent per-lane state ----
    f32x4 vv[16];               // fp32 carry (exact)
    unsigned fpk[16][2];        // bf16(h*f) packed
    bf16x8 uf[2][8];            // U^T A-frags, read-only -> AGPR

    // ---- v loads first (needed by first phase A) ----
    #pragma unroll
    for(int dt=0;dt<16;++dt) vv[dt] = *(const f32x4*)&v_in[gb+dt*16];

    // ---- build uf straight from global (L2-hot 32KB) ----
    #pragma unroll
    for(int rt=0;rt<2;++rt){
        #pragma unroll
        for(int cc=0;cc<8;++cc){
            bf16x8 e;
            #pragma unroll
            for(int j=0;j<8;++j){
                const int kk = ((j>>2)<<4) + g*4 + (j&3);    // kmap(g,j)
                e[j] = f2bf(Ug[(cc*32+kk)*32 + rt*16 + c]);  // U[d][r]
            }
            uf[rt][cc] = e;
        }
    }
    // ---- build WF (4 of 16 dt-tiles per wave) into LDS, -HH folded ----
    #pragma unroll
    for(int i=0;i<4;++i){
        const int t = w*4+i;
        bf16x8 e;
        #pragma unroll
        for(int j=0;j<8;++j){
            const int kk = ((j>>2)<<4) + g*4 + (j&3);
            e[j] = f2bf(-HH * Wg[kk*256 + t*16 + c]);        // -HH*W[r][d]
        }
        *(bf16x8*)&WF[t*512 + lane*8] = e;
    }
    // ---- f -> packed regs ; x -> per-wave LDS xacc (scaled by 1/dt) ----
    #pragma unroll
    for(int dt=0;dt<16;++dt){
        f32x4 ff = *(const f32x4*)&f_in[gb+dt*16];
        fpk[dt][0]=cvtpk(HH*ff[0],HH*ff[1]);
        fpk[dt][1]=cvtpk(HH*ff[2],HH*ff[3]);
    }
    #pragma unroll
    for(int dt=0;dt<16;++dt){
        f32x4 xx = *(const f32x4*)&x_in[gb+dt*16];
        f32x4 xs; xs[0]=INV_DT*xx[0]; xs[1]=INV_DT*xx[1];
        xs[2]=INV_DT*xx[2]; xs[3]=INV_DT*xx[3];
        *(f32x4*)&xw[dt*256 + lane*4] = xs;
    }
    __syncthreads();   // WF visible to all waves (only barrier)

    const int nsteps = *steps_p;
    const f32x4 zero = {0.f,0.f,0.f,0.f};

    // ACCX: half-0 (accumulate x). STX: store final x (last half-0). STV: store final v.
#define PHASE_AB(ACCX, STX, STV) do { \
    f32x4 a00=zero,a01=zero,a10=zero,a11=zero; \
    _Pragma("unroll") \
    for(int cc=0;cc<8;++cc){ \
        VP4 vp; \
        vp.u[0]=cvtpk(vv[2*cc][0],  vv[2*cc][1]); \
        vp.u[1]=cvtpk(vv[2*cc][2],  vv[2*cc][3]); \
        vp.u[2]=cvtpk(vv[2*cc+1][0],vv[2*cc+1][1]); \
        vp.u[3]=cvtpk(vv[2*cc+1][2],vv[2*cc+1][3]); \
        if(cc&1){ a01=__builtin_amdgcn_mfma_f32_16x16x32_bf16(uf[0][cc],vp.h,a01,0,0,0); \
                  a11=__builtin_amdgcn_mfma_f32_16x16x32_bf16(uf[1][cc],vp.h,a11,0,0,0); } \
        else    { a00=__builtin_amdgcn_mfma_f32_16x16x32_bf16(uf[0][cc],vp.h,a00,0,0,0); \
                  a10=__builtin_amdgcn_mfma_f32_16x16x32_bf16(uf[1][cc],vp.h,a10,0,0,0); } \
    } \
    { \
        float t00=a00[0]+a01[0], t01=a00[1]+a01[1], t02=a00[2]+a01[2], t03=a00[3]+a01[3]; \
        float t10=a10[0]+a11[0], t11=a10[1]+a11[1], t12=a10[2]+a11[2], t13=a10[3]+a11[3]; \
        VP4 t2; \
        t2.u[0]=cvtpk(t00*t00, t01*t01); \
        t2.u[1]=cvtpk(t02*t02, t03*t03); \
        t2.u[2]=cvtpk(t10*t10, t11*t11); \
        t2.u[3]=cvtpk(t12*t12, t13*t13); \
        _Pragma("unroll") \
        for(int dt=0;dt<16;++dt){ \
            bf16x8 wf=*(bf16x8*)&WF[dt*512 + lane*8]; \
            const unsigned f0=fpk[dt][0], f1=fpk[dt][1]; \
            f32x4 cin; \
            cin[0]=vv[dt][0]+ubflo(f0); \
            cin[1]=vv[dt][1]+ubfhi(f0); \
            cin[2]=vv[dt][2]+ubflo(f1); \
            cin[3]=vv[dt][3]+ubfhi(f1); \
            f32x4 nv=__builtin_amdgcn_mfma_f32_16x16x32_bf16(wf,t2.h,cin,0,0,0); \
            vv[dt]=nv; \
            if(ACCX){ \
                f32x4* xp=(f32x4*)&xw[dt*256 + lane*4]; \
                f32x4 xv=*xp; \
                xv[0]+=nv[0]; xv[1]+=nv[1]; xv[2]+=nv[2]; xv[3]+=nv[3]; \
                if(STX){ \
                    f32x4 xo; \
                    xo[0]=EFF_DT*xv[0]; xo[1]=EFF_DT*xv[1]; \
                    xo[2]=EFF_DT*xv[2]; xo[3]=EFF_DT*xv[3]; \
                    *(f32x4*)&out[gb+dt*16] = xo; \
                }else{ \
                    *xp = xv; \
                } \
            } \
            if(STV){ \
                *(f32x4*)&out[BD+gb+dt*16] = nv; \
            } \
        } \
    } \
} while(0)

    for(int s=0;s<nsteps-1;++s){
        PHASE_AB(1,0,0);   // half 0: v_half ; xacc += v_half
        PHASE_AB(0,0,0);   // half 1: v update
    }
    PHASE_AB(1,1,0);       // last half 0: x final -> store x (write drains early)
    PHASE_AB(0,0,1);       // last half 1: v final -> store v
#undef PHASE_AB
}

extern "C" void kernel_launch(void* const* d_in, const int* in_sizes, int n_in,
                              void* d_out, int out_size, void* d_ws, size_t ws_size,
                              hipStream_t stream) {
    (void)in_sizes; (void)n_in; (void)d_ws; (void)ws_size; (void)out_size;
    const float* x_in = (const float*)d_in[0];
    const float* v_in = (const float*)d_in[1];
    const float* f_in = (const float*)d_in[2];
    const float* Ug   = (const float*)d_in[3];
    const float* Wg   = (const float*)d_in[4];
    const int*   st   = (const int*)d_in[5];
    float* out = (float*)d_out;

    dim3 grid(32768/64), block(256);
    hipLaunchKernelGGL(leapfrog_v10, grid, block, 0, stream,
                       x_in, v_in, f_in, Ug, Wg, st, out);
}